// Round 3
// baseline (22.356 us; speedup 1.0000x reference)
//
#include <hip/hip_runtime.h>
#include <math.h>

#define NB 128   // batch
#define NL 16    // num_site
#define NM 32    // M
#define NP 4     // P
#define NMP 128  // M*P
#define GRID (2 * NB)

// One fused kernel. 2 blocks per batch element b (h = k-half). 512 threads.
// Thread owns TWO j-rows in registers (j = lane, lane+64); wave w owns k-chunk
// of 8. Each cs[l][k] LDS read is wave-uniform (broadcast) and feeds 2 pairs.
// Last block (device atomic counter) computes the final loss scalar.
__global__ __launch_bounds__(512) void fused_kernel(
    const float* __restrict__ ds, const float* __restrict__ theta,
    const float* __restrict__ coef, float* __restrict__ wnorm,
    float* __restrict__ wamp, unsigned int* __restrict__ counter,
    float* __restrict__ out)
{
    const int b    = blockIdx.x >> 1;
    const int h    = blockIdx.x & 1;
    const int t    = threadIdx.x;
    const int lane = t & 63;
    const int w    = t >> 6;      // wave id 0..7

    __shared__ float2 cs[NL][NMP];   // (cos, sin) of u[l][j]
    __shared__ float  co[NMP];
    __shared__ float  dsrow[NL];
    __shared__ float  redN[8], redA[8];
    __shared__ float  r5[5][8];
    __shared__ bool   s_last;

    if (t < NL)  dsrow[t] = ds[b * NL + t];
    if (t < NMP) co[t]    = coef[t];
    __syncthreads();

    // 2048 sincos, 4 per thread (fast intrinsic; |u| < 3)
    for (int i = t; i < NL * NMP; i += 512) {
        int l = i >> 7;
        int j = i & (NMP - 1);
        int p = j & 3;
        float sf = (float)M_PI / (float)(2 << p);   // pi / 2^(p+1)
        float u  = theta[i] + sf * dsrow[l];
        float ss, cc;
        __sincosf(u, &ss, &cc);
        cs[l][j] = make_float2(cc, ss);
    }
    __syncthreads();

    // two j-rows into registers (64 VGPRs)
    float rc0[NL], rs0[NL], rc1[NL], rs1[NL];
    #pragma unroll
    for (int l = 0; l < NL; ++l) {
        float2 v0 = cs[l][lane];      rc0[l] = v0.x; rs0[l] = v0.y;
        float2 v1 = cs[l][lane + 64]; rc1[l] = v1.x; rs1[l] = v1.y;
    }
    const float wj0 = co[lane], wj1 = co[lane + 64];

    // amp partial: wave 0 only (both halves compute it; only h==0 writes)
    float amp_part = 0.f;
    if (w == 0) {
        float p0 = wj0, p1 = wj1;
        #pragma unroll
        for (int l = 0; l < NL; ++l) { p0 *= rc0[l]; p1 *= rc1[l]; }
        amp_part = p0 + p1;
    }

    // 8 k per wave; cs[l][k] is wave-uniform -> LDS broadcast
    float norm_part = 0.f;
    const int k0 = h * 64 + w * 8;
    #pragma unroll 4
    for (int ki = 0; ki < 8; ++ki) {
        int k = k0 + ki;
        float pp0 = 1.f, pp1 = 1.f;
        #pragma unroll
        for (int l = 0; l < NL; ++l) {
            float2 v = cs[l][k];
            pp0 *= fmaf(rc0[l], v.x, rs0[l] * v.y);   // cos(u_j0 - u_k)
            pp1 *= fmaf(rc1[l], v.x, rs1[l] * v.y);   // cos(u_j1 - u_k)
        }
        norm_part = fmaf(fmaf(wj1, pp1, wj0 * pp0), co[k], norm_part);
    }

    // wave64 butterfly + cross-wave reduce
    #pragma unroll
    for (int off = 32; off > 0; off >>= 1) {
        norm_part += __shfl_xor(norm_part, off);
        amp_part  += __shfl_xor(amp_part,  off);
    }
    if (lane == 0) { redN[w] = norm_part; redA[w] = amp_part; }
    __syncthreads();
    if (t == 0) {
        float n = 0.f, a = 0.f;
        #pragma unroll
        for (int i = 0; i < 8; ++i) { n += redN[i]; a += redA[i]; }
        wnorm[b * 2 + h] = n;
        if (h == 0) wamp[b] = a;
        __threadfence();
        unsigned int old = atomicAdd(counter, 1u);
        s_last = (old == GRID - 1);
    }
    __syncthreads();
    if (!s_last) return;

    // ---- finalize in the last block (512 threads) ----
    volatile const float* vn = wnorm;
    volatile const float* va = wamp;

    float mnl = 0.f;
    if (t < NB) {
        float a = va[t];
        float n = vn[2 * t] + vn[2 * t + 1];
        mnl = -__logf(a * a / n + 1e-20f);
    }
    float cv = (t < NMP) ? co[t] : 0.f;

    // reg_theta_m: 64 (l,p) items, var over M, ddof=1 (theta is L1-warm)
    float vm = 0.f;
    if (t < NL * NP) {
        int l = t >> 2, p = t & 3;
        float sum = 0.f, sum2 = 0.f;
        for (int m = 0; m < NM; ++m) {
            float x = theta[(l * NM + m) * NP + p];
            sum += x; sum2 += x * x;
        }
        vm = (sum2 - sum * sum / (float)NM) / (float)(NM - 1);
    }

    // reg_theta_p: 512 (l,m) items, exactly one per thread, var over P=4
    float4 th = reinterpret_cast<const float4*>(theta)[t];
    float sum  = th.x + th.y + th.z + th.w;
    float sum2 = th.x * th.x + th.y * th.y + th.z * th.z + th.w * th.w;
    float vp = (sum2 - sum * sum * 0.25f) * (1.f / 3.f);

    float v1 = mnl, v2 = cv, v3 = cv * cv, v4 = vm, v5 = vp;
    #pragma unroll
    for (int off = 32; off > 0; off >>= 1) {
        v1 += __shfl_xor(v1, off);
        v2 += __shfl_xor(v2, off);
        v3 += __shfl_xor(v3, off);
        v4 += __shfl_xor(v4, off);
        v5 += __shfl_xor(v5, off);
    }
    if (lane == 0) {
        r5[0][w] = v1; r5[1][w] = v2; r5[2][w] = v3; r5[3][w] = v4; r5[4][w] = v5;
    }
    __syncthreads();
    if (t == 0) {
        float s1 = 0.f, s2 = 0.f, s3 = 0.f, s4 = 0.f, s5 = 0.f;
        #pragma unroll
        for (int i = 0; i < 8; ++i) {
            s1 += r5[0][i]; s2 += r5[1][i]; s3 += r5[2][i];
            s4 += r5[3][i]; s5 += r5[4][i];
        }
        float s_mnl   = s1 / (float)NB;
        float reg_c   = (s3 - s2 * s2 / (float)NMP) / (float)(NMP - 1);
        float reg_tm  = s4 / (float)(NL * NP);
        float reg_tp  = s5 / (float)(NL * NM);
        out[0] = s_mnl + 0.01f * (reg_c + reg_tm + reg_tp);
        *counter = 0;   // self-reset for next replay
    }
}

extern "C" void kernel_launch(void* const* d_in, const int* in_sizes, int n_in,
                              void* d_out, int out_size, void* d_ws, size_t ws_size,
                              hipStream_t stream) {
    const float* ds    = (const float*)d_in[0];  // (B, L)
    const float* theta = (const float*)d_in[1];  // (L, M, P)
    const float* coef  = (const float*)d_in[2];  // (M, P)
    float* wnorm = (float*)d_ws;                         // 256 floats
    float* wamp  = (float*)d_ws + 2 * NB;                // 128 floats
    unsigned int* counter = (unsigned int*)((float*)d_ws + 3 * NB);
    float* out   = (float*)d_out;

    // counter starts poisoned (0xAA..) before the first timed call
    hipMemsetAsync(counter, 0, sizeof(unsigned int), stream);
    fused_kernel<<<GRID, 512, 0, stream>>>(ds, theta, coef, wnorm, wamp, counter, out);
}

// Round 4
// 12.791 us; speedup vs baseline: 1.7478x; 1.7478x over previous
//
#include <hip/hip_runtime.h>
#include <math.h>

#define NB 128   // batch
#define NL 16    // num_site
#define NM 32    // M
#define NP 4     // P
#define NMP 128  // M*P

// Kernel 1: 2 blocks per batch element b (h = k-half). 512 threads.
// Thread owns TWO j-rows in registers (j = lane, lane+64); wave w owns a
// k-chunk of 8. Each cs[l][k] LDS read is wave-uniform (broadcast) and
// feeds 2 pairs. cos(u_j - u_k) = cos_j*cos_k + sin_j*sin_k.
__global__ __launch_bounds__(512) void per_b_kernel(
    const float* __restrict__ ds, const float* __restrict__ theta,
    const float* __restrict__ coef, float* __restrict__ wnorm,
    float* __restrict__ wamp)
{
    const int b    = blockIdx.x >> 1;
    const int h    = blockIdx.x & 1;
    const int t    = threadIdx.x;
    const int lane = t & 63;
    const int w    = t >> 6;      // wave id 0..7

    __shared__ float2 cs[NL][NMP];   // (cos, sin) of u[l][j]
    __shared__ float  co[NMP];
    __shared__ float  dsrow[NL];
    __shared__ float  redN[8], redA[8];

    if (t < NL)  dsrow[t] = ds[b * NL + t];
    if (t < NMP) co[t]    = coef[t];
    __syncthreads();

    // 2048 sincos, 4 per thread (fast intrinsic; |u| < 3, accuracy verified R3)
    for (int i = t; i < NL * NMP; i += 512) {
        int l = i >> 7;
        int j = i & (NMP - 1);
        int p = j & 3;
        float sf = (float)M_PI / (float)(2 << p);   // pi / 2^(p+1)
        float u  = theta[i] + sf * dsrow[l];
        float ss, cc;
        __sincosf(u, &ss, &cc);
        cs[l][j] = make_float2(cc, ss);
    }
    __syncthreads();

    // two j-rows into registers (64 VGPRs)
    float rc0[NL], rs0[NL], rc1[NL], rs1[NL];
    #pragma unroll
    for (int l = 0; l < NL; ++l) {
        float2 v0 = cs[l][lane];      rc0[l] = v0.x; rs0[l] = v0.y;
        float2 v1 = cs[l][lane + 64]; rc1[l] = v1.x; rs1[l] = v1.y;
    }
    const float wj0 = co[lane], wj1 = co[lane + 64];

    // amp partial: wave 0 only
    float amp_part = 0.f;
    if (w == 0) {
        float p0 = wj0, p1 = wj1;
        #pragma unroll
        for (int l = 0; l < NL; ++l) { p0 *= rc0[l]; p1 *= rc1[l]; }
        amp_part = p0 + p1;
    }

    // 8 k per wave; cs[l][k] wave-uniform -> LDS broadcast, feeds both rows
    float norm_part = 0.f;
    const int k0 = h * 64 + w * 8;
    #pragma unroll 4
    for (int ki = 0; ki < 8; ++ki) {
        int k = k0 + ki;
        float pp0 = 1.f, pp1 = 1.f;
        #pragma unroll
        for (int l = 0; l < NL; ++l) {
            float2 v = cs[l][k];
            pp0 *= fmaf(rc0[l], v.x, rs0[l] * v.y);
            pp1 *= fmaf(rc1[l], v.x, rs1[l] * v.y);
        }
        norm_part = fmaf(fmaf(wj1, pp1, wj0 * pp0), co[k], norm_part);
    }

    // wave64 butterfly + cross-wave reduce
    #pragma unroll
    for (int off = 32; off > 0; off >>= 1) {
        norm_part += __shfl_xor(norm_part, off);
        amp_part  += __shfl_xor(amp_part,  off);
    }
    if (lane == 0) { redN[w] = norm_part; redA[w] = amp_part; }
    __syncthreads();
    if (t == 0) {
        float n = 0.f, a = 0.f;
        #pragma unroll
        for (int i = 0; i < 8; ++i) { n += redN[i]; a += redA[i]; }
        wnorm[b * 2 + h] = n;
        if (h == 0) wamp[b] = a;
    }
}

// Kernel 2: single block, 512 threads.
// mean(-log(amp^2/norm + eps)) + 0.01*(reg_c + reg_theta_m + reg_theta_p)
__global__ __launch_bounds__(512) void finalize_kernel(
    const float* __restrict__ wnorm, const float* __restrict__ wamp,
    const float* __restrict__ theta, const float* __restrict__ coef,
    float* __restrict__ out)
{
    const int t    = threadIdx.x;
    const int lane = t & 63;
    const int w    = t >> 6;
    __shared__ float r5[5][8];

    // per-b neg-logs (t < 128)
    float mnl = 0.f;
    if (t < NB) {
        float a = wamp[t];
        float n = wnorm[2 * t] + wnorm[2 * t + 1];
        mnl = -__logf(a * a / n + 1e-20f);
    }
    float cv = (t < NMP) ? coef[t] : 0.f;

    // reg_theta_m: 64 (l,p) items, var over M, ddof=1
    float vm = 0.f;
    if (t < NL * NP) {
        int l = t >> 2, p = t & 3;
        float sum = 0.f, sum2 = 0.f;
        for (int m = 0; m < NM; ++m) {
            float x = theta[(l * NM + m) * NP + p];
            sum += x; sum2 += x * x;
        }
        vm = (sum2 - sum * sum / (float)NM) / (float)(NM - 1);
    }

    // reg_theta_p: 512 (l,m) items, exactly one float4 per thread
    float4 th = reinterpret_cast<const float4*>(theta)[t];
    float sum  = th.x + th.y + th.z + th.w;
    float sum2 = th.x * th.x + th.y * th.y + th.z * th.z + th.w * th.w;
    float vp = (sum2 - sum * sum * 0.25f) * (1.f / 3.f);

    float v1 = mnl, v2 = cv, v3 = cv * cv, v4 = vm, v5 = vp;
    #pragma unroll
    for (int off = 32; off > 0; off >>= 1) {
        v1 += __shfl_xor(v1, off);
        v2 += __shfl_xor(v2, off);
        v3 += __shfl_xor(v3, off);
        v4 += __shfl_xor(v4, off);
        v5 += __shfl_xor(v5, off);
    }
    if (lane == 0) {
        r5[0][w] = v1; r5[1][w] = v2; r5[2][w] = v3; r5[3][w] = v4; r5[4][w] = v5;
    }
    __syncthreads();
    if (t == 0) {
        float s1 = 0.f, s2 = 0.f, s3 = 0.f, s4 = 0.f, s5 = 0.f;
        #pragma unroll
        for (int i = 0; i < 8; ++i) {
            s1 += r5[0][i]; s2 += r5[1][i]; s3 += r5[2][i];
            s4 += r5[3][i]; s5 += r5[4][i];
        }
        float s_mnl  = s1 / (float)NB;
        float reg_c  = (s3 - s2 * s2 / (float)NMP) / (float)(NMP - 1);
        float reg_tm = s4 / (float)(NL * NP);
        float reg_tp = s5 / (float)(NL * NM);
        out[0] = s_mnl + 0.01f * (reg_c + reg_tm + reg_tp);
    }
}

extern "C" void kernel_launch(void* const* d_in, const int* in_sizes, int n_in,
                              void* d_out, int out_size, void* d_ws, size_t ws_size,
                              hipStream_t stream) {
    const float* ds    = (const float*)d_in[0];  // (B, L)
    const float* theta = (const float*)d_in[1];  // (L, M, P)
    const float* coef  = (const float*)d_in[2];  // (M, P)
    float* wnorm = (float*)d_ws;                 // 256 floats
    float* wamp  = (float*)d_ws + 2 * NB;        // 128 floats
    float* out   = (float*)d_out;

    per_b_kernel<<<2 * NB, 512, 0, stream>>>(ds, theta, coef, wnorm, wamp);
    finalize_kernel<<<1, 512, 0, stream>>>(wnorm, wamp, theta, coef, out);
}